// Round 3
// baseline (768.256 us; speedup 1.0000x reference)
//
#include <hip/hip_runtime.h>
#include <hip/hip_fp16.h>

typedef __bf16 bf16;
typedef bf16 bf16x8 __attribute__((ext_vector_type(8)));
typedef float f32x4 __attribute__((ext_vector_type(4)));

#define LD64  80   // padded LDS row stride (elems) for 64-wide tiles
#define LD128 144  // padded LDS row stride for 128-wide tiles

// Barrier that drains ONLY lgkmcnt (LDS visibility); does not drain vmcnt.
#define BAR_LGKM() asm volatile("s_waitcnt lgkmcnt(0)\n\ts_barrier" ::: "memory")

static __device__ __forceinline__ f32x4 mfma16(bf16x8 a, bf16x8 b, f32x4 c) {
    return __builtin_amdgcn_mfma_f32_16x16x32_bf16(a, b, c, 0, 0, 0);
}

static __device__ __forceinline__ bf16x8 cvt8(float4 a, float4 b) {
    bf16x8 v;
    v[0] = (bf16)a.x; v[1] = (bf16)a.y; v[2] = (bf16)a.z; v[3] = (bf16)a.w;
    v[4] = (bf16)b.x; v[5] = (bf16)b.y; v[6] = (bf16)b.z; v[7] = (bf16)b.w;
    return v;
}

// --- helpers for the fallback (f16 agg) path ---
static __device__ __forceinline__ uint32_t pack_f16(float lo, float hi) {
    __half hl = __float2half_rn(lo), hh = __float2half_rn(hi);
    uint16_t a = *(uint16_t*)&hl, b = *(uint16_t*)&hh;
    return ((uint32_t)b << 16) | (uint32_t)a;
}
static __device__ __forceinline__ void atomic_pk_f16(__half* addr, uint32_t v) {
    asm volatile("global_atomic_pk_add_f16 %0, %1, off" :: "v"(addr), "v"(v) : "memory");
}
static __device__ __forceinline__ float h2f_lo(uint32_t u) {
    uint16_t s = (uint16_t)u; __half h = *(__half*)&s; return __half2float(h);
}
static __device__ __forceinline__ float h2f_hi(uint32_t u) {
    uint16_t s = (uint16_t)(u >> 16); __half h = *(__half*)&s; return __half2float(h);
}

// ===========================================================================
// Sort infrastructure: counting sort of rel2 (edge,slot) entries by dest node.
// ===========================================================================

// histogram: cnt1[id] for rel1 (multiplier), cnt2[id] for rel2 sort bins
__global__ __launch_bounds__(256) void hist_kernel(
    const int* __restrict__ r1, const int* __restrict__ r2,
    unsigned* __restrict__ cnt1, unsigned* __restrict__ cnt2, int M1, int M2x2)
{
    int i = blockIdx.x * 256 + threadIdx.x;
    const int T = gridDim.x * 256;
    const int tot = M1 + M2x2;
    for (; i < tot; i += T) {
        if (i < M1) atomicAdd(&cnt1[r1[i]], 1u);
        else        atomicAdd(&cnt2[r2[i - M1]], 1u);
    }
}

// per-chunk (512-bin) sums of cnt2
__global__ __launch_bounds__(256) void scan_sums(
    const unsigned* __restrict__ cnt, unsigned* __restrict__ csum)
{
    __shared__ unsigned s[256];
    const int b = blockIdx.x, t = threadIdx.x;
    s[t] = cnt[b * 512 + t] + cnt[b * 512 + 256 + t];
    __syncthreads();
    for (int d = 128; d > 0; d >>= 1) {
        if (t < d) s[t] += s[t + d];
        __syncthreads();
    }
    if (t == 0) csum[b] = s[0];
}

// serial exclusive scan of chunk sums (nch ~196, trivial)
__global__ void scan_chunkoff(unsigned* __restrict__ csum, int nch) {
    if (blockIdx.x == 0 && threadIdx.x == 0) {
        unsigned run = 0;
        for (int j = 0; j < nch; ++j) { unsigned v = csum[j]; csum[j] = run; run += v; }
    }
}

// in-place: cnt2[i] <- global exclusive prefix (start offsets)
__global__ __launch_bounds__(256) void scan_apply(
    unsigned* __restrict__ cnt, const unsigned* __restrict__ csum)
{
    __shared__ unsigned s[2][512];
    const int b = blockIdx.x, t = threadIdx.x;
    const unsigned base = csum[b];
    s[0][t] = cnt[b * 512 + t];
    s[0][t + 256] = cnt[b * 512 + t + 256];
    __syncthreads();
    int src = 0;
    for (int d = 1; d < 512; d <<= 1) {
        int dst = src ^ 1;
        for (int i = t; i < 512; i += 256)
            s[dst][i] = s[src][i] + (i >= d ? s[src][i - d] : 0u);
        __syncthreads();
        src = dst;
    }
    for (int i = t; i < 512; i += 256)
        cnt[b * 512 + i] = base + s[src][i] - cnt[b * 512 + i];  // exclusive
}

// placement: stream sorted by destination; payload = flat index into r2
__global__ __launch_bounds__(256) void place_kernel(
    const int* __restrict__ r2, unsigned* __restrict__ cur,
    unsigned* __restrict__ sid, unsigned* __restrict__ spl, int M2x2)
{
    int i = blockIdx.x * 256 + threadIdx.x;
    const int T = gridDim.x * 256;
    for (; i < M2x2; i += T) {
        int id = r2[i];
        unsigned p = atomicAdd(&cur[id], 1u);
        sid[p] = (unsigned)id;
        spl[p] = (unsigned)i;
    }
}

// ===========================================================================
// rel1 dense: agg[n] = cnt1[n] * (relu(emb[n]@W1+b1)@W2 + b2). No atomics.
// Writes EVERY agg row (replaces the agg memset).
// ===========================================================================
__global__ __launch_bounds__(256) void rel1_dense_kernel(
    const float* __restrict__ emb, const unsigned* __restrict__ cnt,
    const float* __restrict__ W1, const float* __restrict__ b1,
    const float* __restrict__ W2, const float* __restrict__ b2,
    float* __restrict__ agg, int N, int numTiles)
{
    __shared__ bf16 sW1t[64 * LD64];
    __shared__ bf16 sW2t[64 * LD64];
    __shared__ bf16 sG[64 * LD64];
    __shared__ bf16 sH[64 * LD64];
    __shared__ float sB1[64], sB2[64];
    __shared__ float sCnt[64];

    const int t = threadIdx.x;
    const int wave = t >> 6, lane = t & 63;
    const int l15 = lane & 15, quad = lane >> 4;
    const int r = t >> 2, p = t & 3;

    for (int i = t; i < 64 * 64; i += 256) {
        int k = i >> 6, n = i & 63;
        sW1t[n * LD64 + k] = (bf16)W1[i];
        sW2t[n * LD64 + k] = (bf16)W2[i];
    }
    if (t < 64) { sB1[t] = b1[t]; sB2[t] = b2[t]; }

    for (int tile = blockIdx.x; tile < numTiles; tile += gridDim.x) {
        __syncthreads();
        const int base = tile * 64;
        const int R = base + r;
        if (R < N) {
            if (p == 0) sCnt[r] = (float)cnt[R];
            const float4* src = (const float4*)(emb + (size_t)R * 64 + p * 16);
            float4 v0 = src[0], v1 = src[1], v2 = src[2], v3 = src[3];
            *(bf16x8*)&sG[r * LD64 + p * 16 + 0] = cvt8(v0, v1);
            *(bf16x8*)&sG[r * LD64 + p * 16 + 8] = cvt8(v2, v3);
        } else if (p == 0) sCnt[r] = 0.f;
        __syncthreads();

        // GEMM1: h = relu(g @ W1 + b1)
        f32x4 acc[4];
        #pragma unroll
        for (int nt = 0; nt < 4; ++nt) acc[nt] = (f32x4){0.f, 0.f, 0.f, 0.f};
        #pragma unroll
        for (int kt = 0; kt < 2; ++kt) {
            bf16x8 a = *(const bf16x8*)&sG[(wave * 16 + l15) * LD64 + kt * 32 + quad * 8];
            #pragma unroll
            for (int nt = 0; nt < 4; ++nt) {
                bf16x8 bfr = *(const bf16x8*)&sW1t[(nt * 16 + l15) * LD64 + kt * 32 + quad * 8];
                acc[nt] = mfma16(a, bfr, acc[nt]);
            }
        }
        #pragma unroll
        for (int nt = 0; nt < 4; ++nt) {
            float bias = sB1[nt * 16 + l15];
            #pragma unroll
            for (int rr = 0; rr < 4; ++rr) {
                float v = acc[nt][rr] + bias;
                v = v > 0.f ? v : 0.f;
                sH[(wave * 16 + quad * 4 + rr) * LD64 + nt * 16 + l15] = (bf16)v;
            }
        }
        __syncthreads();

        // GEMM2 + scaled dense store
        f32x4 acc2[4];
        #pragma unroll
        for (int nt = 0; nt < 4; ++nt) acc2[nt] = (f32x4){0.f, 0.f, 0.f, 0.f};
        #pragma unroll
        for (int kt = 0; kt < 2; ++kt) {
            bf16x8 a = *(const bf16x8*)&sH[(wave * 16 + l15) * LD64 + kt * 32 + quad * 8];
            #pragma unroll
            for (int nt = 0; nt < 4; ++nt) {
                bf16x8 bfr = *(const bf16x8*)&sW2t[(nt * 16 + l15) * LD64 + kt * 32 + quad * 8];
                acc2[nt] = mfma16(a, bfr, acc2[nt]);
            }
        }
        #pragma unroll
        for (int nt = 0; nt < 4; ++nt) {
            float bias = sB2[nt * 16 + l15];
            #pragma unroll
            for (int rr = 0; rr < 4; ++rr) {
                int row = wave * 16 + quad * 4 + rr;
                int R2 = base + row;
                if (R2 < N)
                    agg[(size_t)R2 * 64 + nt * 16 + l15] = sCnt[row] * (acc2[nt][rr] + bias);
            }
        }
    }
}

// ===========================================================================
// rel2 aggregation over the destination-sorted stream.
// Per tile: 64 sorted entries; recompute edge MLP (128-wide); keep the slot's
// 64-col half; run-length sum per column over sorted ids; one f32 atomic/run.
// ===========================================================================
__global__ __launch_bounds__(256) void rel2_agg_kernel(
    const float* __restrict__ emb, const int* __restrict__ idx,   // rel2 flat [2*M2]
    const unsigned* __restrict__ sid, const unsigned* __restrict__ spl,
    const float* __restrict__ W1, const float* __restrict__ b1,   // 128x128, 128
    const float* __restrict__ W2, const float* __restrict__ b2,
    float* __restrict__ agg, int S, int numTiles)
{
    __shared__ bf16 sG[64 * LD128];   // staging for GEMM1; reused as sM after
    __shared__ bf16 sH[64 * LD128];
    __shared__ int sSid[64];
    __shared__ int sSlot[64];

    const int t = threadIdx.x;
    const int wave = t >> 6, lane = t & 63;
    const int l15 = lane & 15, quad = lane >> 4;
    const int r = t >> 2, p = t & 3;

    // per-wave B fragments in registers: n-tiles {2*wave, 2*wave+1}
    bf16x8 w1f[2][4], w2f[2][4];
    float bias1[2], bias2[2];
    #pragma unroll
    for (int j = 0; j < 2; ++j) {
        const int n = (wave * 2 + j) * 16 + l15;
        bias1[j] = b1[n];
        bias2[j] = b2[n];
        #pragma unroll
        for (int kt = 0; kt < 4; ++kt) {
            bf16x8 f1, f2;
            #pragma unroll
            for (int e = 0; e < 8; ++e) {
                int k = kt * 32 + quad * 8 + e;
                f1[e] = (bf16)W1[k * 128 + n];
                f2[e] = (bf16)W2[k * 128 + n];
            }
            w1f[j][kt] = f1;
            w2f[j][kt] = f2;
        }
    }

    for (int tile = blockIdx.x; tile < numTiles; tile += gridDim.x) {
        __syncthreads();   // protect sG(=sM)/sSid/sSlot reuse vs previous epilogue
        const int base = tile * 64;
        const int R = base + r;
        int id = -1, pl = 0;
        if (R < S) { id = (int)sid[R]; pl = (int)spl[R]; }
        if (p == 0) { sSid[r] = id; sSlot[r] = pl & 1; }
        if (id >= 0) {
            const int e2 = pl & ~1;
            const int i0 = idx[e2], i1 = idx[e2 + 1];
            const int srcId = (p < 2) ? i0 : i1;
            const float4* src = (const float4*)(emb + (size_t)srcId * 64 + (p & 1) * 32);
            #pragma unroll
            for (int i = 0; i < 4; ++i) {
                float4 va = src[2 * i], vb = src[2 * i + 1];
                *(bf16x8*)&sG[r * LD128 + p * 32 + i * 8] = cvt8(va, vb);
            }
        }
        __syncthreads();

        // GEMM1 over all 4 m-tiles, this wave's 2 n-tiles
        f32x4 acc[4][2];
        #pragma unroll
        for (int mt = 0; mt < 4; ++mt)
            #pragma unroll
            for (int j = 0; j < 2; ++j) acc[mt][j] = (f32x4){0.f, 0.f, 0.f, 0.f};
        #pragma unroll
        for (int mt = 0; mt < 4; ++mt) {
            #pragma unroll
            for (int kt = 0; kt < 4; ++kt) {
                bf16x8 a = *(const bf16x8*)&sG[(mt * 16 + l15) * LD128 + kt * 32 + quad * 8];
                #pragma unroll
                for (int j = 0; j < 2; ++j) acc[mt][j] = mfma16(a, w1f[j][kt], acc[mt][j]);
            }
        }
        #pragma unroll
        for (int mt = 0; mt < 4; ++mt)
            #pragma unroll
            for (int j = 0; j < 2; ++j) {
                #pragma unroll
                for (int rr = 0; rr < 4; ++rr) {
                    float v = acc[mt][j][rr] + bias1[j];
                    v = v > 0.f ? v : 0.f;
                    sH[(mt * 16 + quad * 4 + rr) * LD128 + (wave * 2 + j) * 16 + l15] = (bf16)v;
                }
            }
        __syncthreads();

        // GEMM2 -> write m-tile (with bias2) into sM (= sG)
        f32x4 acc2[4][2];
        #pragma unroll
        for (int mt = 0; mt < 4; ++mt)
            #pragma unroll
            for (int j = 0; j < 2; ++j) acc2[mt][j] = (f32x4){0.f, 0.f, 0.f, 0.f};
        #pragma unroll
        for (int mt = 0; mt < 4; ++mt) {
            #pragma unroll
            for (int kt = 0; kt < 4; ++kt) {
                bf16x8 a = *(const bf16x8*)&sH[(mt * 16 + l15) * LD128 + kt * 32 + quad * 8];
                #pragma unroll
                for (int j = 0; j < 2; ++j) acc2[mt][j] = mfma16(a, w2f[j][kt], acc2[mt][j]);
            }
        }
        #pragma unroll
        for (int mt = 0; mt < 4; ++mt)
            #pragma unroll
            for (int j = 0; j < 2; ++j) {
                #pragma unroll
                for (int rr = 0; rr < 4; ++rr)
                    sG[(mt * 16 + quad * 4 + rr) * LD128 + (wave * 2 + j) * 16 + l15] =
                        (bf16)(acc2[mt][j][rr] + bias2[j]);
            }
        __syncthreads();

        // epilogue: run-length segment sum per column over sorted ids
        {
            const int c = t & 63;        // output column
            const int seg = t >> 6;      // 16-row segment
            int cur = -1;
            float run = 0.f;
            #pragma unroll
            for (int k = 0; k < 16; ++k) {
                const int row = seg * 16 + k;
                const int id2 = sSid[row];
                if (id2 != cur) {
                    if (cur >= 0) atomicAdd(&agg[(size_t)cur * 64 + c], run);
                    run = 0.f;
                    cur = id2;
                }
                if (cur >= 0)
                    run += (float)sG[row * LD128 + sSlot[row] * 64 + c];
            }
            if (cur >= 0) atomicAdd(&agg[(size_t)cur * 64 + c], run);
        }
    }
}

// ===========================================================================
// update: out = relu([emb||agg] @ W1 + b1) @ W2 + b2   (agg f32)
// ===========================================================================
__global__ __launch_bounds__(256) void update_kernel(
    const float* __restrict__ emb, const float* __restrict__ agg,
    const float* __restrict__ W1, const float* __restrict__ b1,  // 128x64, 64
    const float* __restrict__ W2, const float* __restrict__ b2,  // 64x64, 64
    float* __restrict__ out, int N, int numTiles)
{
    __shared__ bf16 sW1t[64 * LD128];
    __shared__ bf16 sW2t[64 * LD64];
    __shared__ bf16 sU[64 * LD128];
    __shared__ bf16 sH[64 * LD64];
    __shared__ float sB1[64], sB2[64];

    const int t = threadIdx.x;
    const int wave = t >> 6, lane = t & 63;
    const int l15 = lane & 15, quad = lane >> 4;
    const int r = t >> 2, p = t & 3;

    for (int i = t; i < 128 * 64; i += 256) {
        int k = i >> 6, n = i & 63;
        sW1t[n * LD128 + k] = (bf16)W1[i];
    }
    for (int i = t; i < 64 * 64; i += 256) {
        int k = i >> 6, n = i & 63;
        sW2t[n * LD64 + k] = (bf16)W2[i];
    }
    if (t < 64) { sB1[t] = b1[t]; sB2[t] = b2[t]; }

    for (int tile = blockIdx.x; tile < numTiles; tile += gridDim.x) {
        __syncthreads();
        const int base = tile * 64;
        {
            const int R = base + r;
            if (R < N) {
                const float* srcp = (p < 2) ? (emb + (size_t)R * 64 + p * 32)
                                            : (agg + (size_t)R * 64 + (p - 2) * 32);
                const float4* src = (const float4*)srcp;
                #pragma unroll
                for (int i = 0; i < 4; ++i)
                    *(bf16x8*)&sU[r * LD128 + p * 32 + i * 8] = cvt8(src[2 * i], src[2 * i + 1]);
            }
        }
        __syncthreads();

        f32x4 acc[4];
        #pragma unroll
        for (int nt = 0; nt < 4; ++nt) acc[nt] = (f32x4){0.f, 0.f, 0.f, 0.f};
        #pragma unroll
        for (int kt = 0; kt < 4; ++kt) {
            bf16x8 a = *(const bf16x8*)&sU[(wave * 16 + l15) * LD128 + kt * 32 + quad * 8];
            #pragma unroll
            for (int nt = 0; nt < 4; ++nt) {
                bf16x8 bfr = *(const bf16x8*)&sW1t[(nt * 16 + l15) * LD128 + kt * 32 + quad * 8];
                acc[nt] = mfma16(a, bfr, acc[nt]);
            }
        }
        #pragma unroll
        for (int nt = 0; nt < 4; ++nt) {
            float bias = sB1[nt * 16 + l15];
            #pragma unroll
            for (int rr = 0; rr < 4; ++rr) {
                float v = acc[nt][rr] + bias;
                v = v > 0.f ? v : 0.f;
                sH[(wave * 16 + quad * 4 + rr) * LD64 + nt * 16 + l15] = (bf16)v;
            }
        }
        __syncthreads();

        f32x4 acc2[4];
        #pragma unroll
        for (int nt = 0; nt < 4; ++nt) acc2[nt] = (f32x4){0.f, 0.f, 0.f, 0.f};
        #pragma unroll
        for (int kt = 0; kt < 2; ++kt) {
            bf16x8 a = *(const bf16x8*)&sH[(wave * 16 + l15) * LD64 + kt * 32 + quad * 8];
            #pragma unroll
            for (int nt = 0; nt < 4; ++nt) {
                bf16x8 bfr = *(const bf16x8*)&sW2t[(nt * 16 + l15) * LD64 + kt * 32 + quad * 8];
                acc2[nt] = mfma16(a, bfr, acc2[nt]);
            }
        }
        #pragma unroll
        for (int nt = 0; nt < 4; ++nt) {
            float bias = sB2[nt * 16 + l15];
            #pragma unroll
            for (int rr = 0; rr < 4; ++rr) {
                int row = wave * 16 + quad * 4 + rr;
                int R = base + row;
                if (R < N)
                    out[(size_t)R * 64 + nt * 16 + l15] = acc2[nt][rr] + bias;
            }
        }
    }
}

// ===========================================================================
// Fallback path (workspace too small): Round-1 kernels (f16 agg, pk atomics).
// ===========================================================================
__global__ __launch_bounds__(256) void rel1_fb_kernel(
    const float* __restrict__ emb, const int* __restrict__ idx,
    const float* __restrict__ W1, const float* __restrict__ b1,
    const float* __restrict__ W2, const float* __restrict__ b2,
    __half* __restrict__ agg, int M, int numTiles)
{
    __shared__ bf16 sW1t[64 * LD64];
    __shared__ bf16 sW2t[64 * LD64];
    __shared__ bf16 sG[64 * LD64];
    __shared__ bf16 sH[64 * LD64];
    __shared__ float sB1[64], sB2[64];
    __shared__ int sIdx[64];

    const int t = threadIdx.x;
    const int wave = t >> 6, lane = t & 63;
    const int l15 = lane & 15, quad = lane >> 4;
    const int r = t >> 2, p = t & 3;

    for (int i = t; i < 64 * 64; i += 256) {
        int k = i >> 6, n = i & 63;
        sW1t[n * LD64 + k] = (bf16)W1[i];
        sW2t[n * LD64 + k] = (bf16)W2[i];
    }
    if (t < 64) { sB1[t] = b1[t]; sB2[t] = b2[t]; }

    for (int tile = blockIdx.x; tile < numTiles; tile += gridDim.x) {
        __syncthreads();
        const int base = tile * 64;
        int id = -1;
        { int R = base + r; if (R < M) id = idx[R]; }
        if (p == 0) sIdx[r] = id;
        if (id >= 0) {
            const float4* src = (const float4*)(emb + (size_t)id * 64 + p * 16);
            float4 v0 = src[0], v1 = src[1], v2 = src[2], v3 = src[3];
            *(bf16x8*)&sG[r * LD64 + p * 16 + 0] = cvt8(v0, v1);
            *(bf16x8*)&sG[r * LD64 + p * 16 + 8] = cvt8(v2, v3);
        }
        __syncthreads();

        f32x4 acc[4];
        #pragma unroll
        for (int nt = 0; nt < 4; ++nt) acc[nt] = (f32x4){0.f, 0.f, 0.f, 0.f};
        #pragma unroll
        for (int kt = 0; kt < 2; ++kt) {
            bf16x8 a = *(const bf16x8*)&sG[(wave * 16 + l15) * LD64 + kt * 32 + quad * 8];
            #pragma unroll
            for (int nt = 0; nt < 4; ++nt) {
                bf16x8 bfr = *(const bf16x8*)&sW1t[(nt * 16 + l15) * LD64 + kt * 32 + quad * 8];
                acc[nt] = mfma16(a, bfr, acc[nt]);
            }
        }
        #pragma unroll
        for (int nt = 0; nt < 4; ++nt) {
            float bias = sB1[nt * 16 + l15];
            #pragma unroll
            for (int rr = 0; rr < 4; ++rr) {
                float v = acc[nt][rr] + bias;
                v = v > 0.f ? v : 0.f;
                sH[(wave * 16 + quad * 4 + rr) * LD64 + nt * 16 + l15] = (bf16)v;
            }
        }
        __syncthreads();

        f32x4 acc2[4];
        #pragma unroll
        for (int nt = 0; nt < 4; ++nt) acc2[nt] = (f32x4){0.f, 0.f, 0.f, 0.f};
        #pragma unroll
        for (int kt = 0; kt < 2; ++kt) {
            bf16x8 a = *(const bf16x8*)&sH[(wave * 16 + l15) * LD64 + kt * 32 + quad * 8];
            #pragma unroll
            for (int nt = 0; nt < 4; ++nt) {
                bf16x8 bfr = *(const bf16x8*)&sW2t[(nt * 16 + l15) * LD64 + kt * 32 + quad * 8];
                acc2[nt] = mfma16(a, bfr, acc2[nt]);
            }
        }
        #pragma unroll
        for (int nt = 0; nt < 4; ++nt) {
            float bias = sB2[nt * 16 + l15];
            const int colb = nt * 16 + (l15 & ~1);
            const int odd = l15 & 1;
            #pragma unroll
            for (int rr = 0; rr < 4; ++rr) {
                float v = acc2[nt][rr] + bias;
                float o = __shfl_xor(v, 1);
                if ((rr >> 1) == odd) {
                    int row = wave * 16 + quad * 4 + rr;
                    int id2 = sIdx[row];
                    if (id2 >= 0)
                        atomic_pk_f16(agg + (size_t)id2 * 64 + colb,
                                      odd ? pack_f16(o, v) : pack_f16(v, o));
                }
            }
        }
    }
}

__global__ __launch_bounds__(256) void rel2_fb_kernel(
    const float* __restrict__ emb, const int* __restrict__ idx,
    const float* __restrict__ W1, const float* __restrict__ b1,
    const float* __restrict__ W2, const float* __restrict__ b2,
    __half* __restrict__ agg, int M, int numTiles)
{
    __shared__ bf16 sG[64 * LD128];
    __shared__ bf16 sH[64 * LD128];
    __shared__ int sIdx[128];

    const int t = threadIdx.x;
    const int wave = t >> 6, lane = t & 63;
    const int l15 = lane & 15, quad = lane >> 4;
    const int r = t >> 2, p = t & 3;

    bf16x8 w1f[2][4], w2f[2][4];
    float bias1[2], bias2[2];
    #pragma unroll
    for (int j = 0; j < 2; ++j) {
        const int n = (wave * 2 + j) * 16 + l15;
        bias1[j] = b1[n];
        bias2[j] = b2[n];
        #pragma unroll
        for (int kt = 0; kt < 4; ++kt) {
            bf16x8 f1, f2;
            #pragma unroll
            for (int e = 0; e < 8; ++e) {
                int k = kt * 32 + quad * 8 + e;
                f1[e] = (bf16)W1[k * 128 + n];
                f2[e] = (bf16)W2[k * 128 + n];
            }
            w1f[j][kt] = f1;
            w2f[j][kt] = f2;
        }
    }

    for (int tile = blockIdx.x; tile < numTiles; tile += gridDim.x) {
        __syncthreads();
        const int base = tile * 64;
        int i0 = -1, i1 = -1;
        { int R = base + r; if (R < M) { i0 = idx[R * 2]; i1 = idx[R * 2 + 1]; } }
        if (p == 0) { sIdx[r * 2] = i0; sIdx[r * 2 + 1] = i1; }
        {
            int myid = (p < 2) ? i0 : i1;
            if (myid >= 0) {
                const float4* src = (const float4*)(emb + (size_t)myid * 64 + (p & 1) * 32);
                #pragma unroll
                for (int i = 0; i < 4; ++i)
                    *(bf16x8*)&sG[r * LD128 + p * 32 + i * 8] = cvt8(src[2 * i], src[2 * i + 1]);
            }
        }
        __syncthreads();

        f32x4 acc[4][2];
        #pragma unroll
        for (int mt = 0; mt < 4; ++mt)
            #pragma unroll
            for (int j = 0; j < 2; ++j) acc[mt][j] = (f32x4){0.f, 0.f, 0.f, 0.f};
        #pragma unroll
        for (int mt = 0; mt < 4; ++mt) {
            #pragma unroll
            for (int kt = 0; kt < 4; ++kt) {
                bf16x8 a = *(const bf16x8*)&sG[(mt * 16 + l15) * LD128 + kt * 32 + quad * 8];
                #pragma unroll
                for (int j = 0; j < 2; ++j) acc[mt][j] = mfma16(a, w1f[j][kt], acc[mt][j]);
            }
        }
        #pragma unroll
        for (int mt = 0; mt < 4; ++mt)
            #pragma unroll
            for (int j = 0; j < 2; ++j) {
                #pragma unroll
                for (int rr = 0; rr < 4; ++rr) {
                    float v = acc[mt][j][rr] + bias1[j];
                    v = v > 0.f ? v : 0.f;
                    sH[(mt * 16 + quad * 4 + rr) * LD128 + (wave * 2 + j) * 16 + l15] = (bf16)v;
                }
            }
        __syncthreads();

        f32x4 acc2[4][2];
        #pragma unroll
        for (int mt = 0; mt < 4; ++mt)
            #pragma unroll
            for (int j = 0; j < 2; ++j) acc2[mt][j] = (f32x4){0.f, 0.f, 0.f, 0.f};
        #pragma unroll
        for (int mt = 0; mt < 4; ++mt) {
            #pragma unroll
            for (int kt = 0; kt < 4; ++kt) {
                bf16x8 a = *(const bf16x8*)&sH[(mt * 16 + l15) * LD128 + kt * 32 + quad * 8];
                #pragma unroll
                for (int j = 0; j < 2; ++j) acc2[mt][j] = mfma16(a, w2f[j][kt], acc2[mt][j]);
            }
        }
        #pragma unroll
        for (int mt = 0; mt < 4; ++mt) {
            #pragma unroll
            for (int j = 0; j < 2; ++j) {
                const int colb = (wave * 2 + j) * 16 + (l15 & ~1);
                const int sel = colb >> 6;
                const int c = colb & 63;
                const int odd = l15 & 1;
                #pragma unroll
                for (int rr = 0; rr < 4; ++rr) {
                    float v = acc2[mt][j][rr] + bias2[j];
                    float o = __shfl_xor(v, 1);
                    if ((rr >> 1) == odd) {
                        int row = mt * 16 + quad * 4 + rr;
                        int id2 = sIdx[row * 2 + sel];
                        if (id2 >= 0)
                            atomic_pk_f16(agg + (size_t)id2 * 64 + c,
                                          odd ? pack_f16(o, v) : pack_f16(v, o));
                    }
                }
            }
        }
    }
}

__global__ __launch_bounds__(256) void update_fb_kernel(
    const float* __restrict__ emb, const __half* __restrict__ agg,
    const float* __restrict__ W1, const float* __restrict__ b1,
    const float* __restrict__ W2, const float* __restrict__ b2,
    float* __restrict__ out, int N, int numTiles)
{
    __shared__ bf16 sW1t[64 * LD128];
    __shared__ bf16 sW2t[64 * LD64];
    __shared__ bf16 sU[64 * LD128];
    __shared__ bf16 sH[64 * LD64];
    __shared__ float sB1[64], sB2[64];

    const int t = threadIdx.x;
    const int wave = t >> 6, lane = t & 63;
    const int l15 = lane & 15, quad = lane >> 4;
    const int r = t >> 2, p = t & 3;

    for (int i = t; i < 128 * 64; i += 256) {
        int k = i >> 6, n = i & 63;
        sW1t[n * LD128 + k] = (bf16)W1[i];
    }
    for (int i = t; i < 64 * 64; i += 256) {
        int k = i >> 6, n = i & 63;
        sW2t[n * LD64 + k] = (bf16)W2[i];
    }
    if (t < 64) { sB1[t] = b1[t]; sB2[t] = b2[t]; }

    for (int tile = blockIdx.x; tile < numTiles; tile += gridDim.x) {
        __syncthreads();
        const int base = tile * 64;
        {
            const int R = base + r;
            if (R < N) {
                if (p < 2) {
                    const float4* src = (const float4*)(emb + (size_t)R * 64 + p * 32);
                    #pragma unroll
                    for (int i = 0; i < 4; ++i)
                        *(bf16x8*)&sU[r * LD128 + p * 32 + i * 8] = cvt8(src[2 * i], src[2 * i + 1]);
                } else {
                    const uint4* src = (const uint4*)(agg + (size_t)R * 64 + (p - 2) * 32);
                    #pragma unroll
                    for (int i = 0; i < 4; ++i) {
                        uint4 u = src[i];
                        bf16x8 o;
                        o[0] = (bf16)h2f_lo(u.x); o[1] = (bf16)h2f_hi(u.x);
                        o[2] = (bf16)h2f_lo(u.y); o[3] = (bf16)h2f_hi(u.y);
                        o[4] = (bf16)h2f_lo(u.z); o[5] = (bf16)h2f_hi(u.z);
                        o[6] = (bf16)h2f_lo(u.w); o[7] = (bf16)h2f_hi(u.w);
                        *(bf16x8*)&sU[r * LD128 + p * 32 + i * 8] = o;
                    }
                }
            }
        }
        __syncthreads();

        f32x4 acc[4];
        #pragma unroll
        for (int nt = 0; nt < 4; ++nt) acc[nt] = (f32x4){0.f, 0.f, 0.f, 0.f};
        #pragma unroll
        for (int kt = 0; kt < 4; ++kt) {
            bf16x8 a = *(const bf16x8*)&sU[(wave * 16 + l15) * LD128 + kt * 32 + quad * 8];
            #pragma unroll
            for (int nt = 0; nt < 4; ++nt) {
                bf16x8 bfr = *(const bf16x8*)&sW1t[(nt * 16 + l15) * LD128 + kt * 32 + quad * 8];
                acc[nt] = mfma16(a, bfr, acc[nt]);
            }
        }
        #pragma unroll
        for (int nt = 0; nt < 4; ++nt) {
            float bias = sB1[nt * 16 + l15];
            #pragma unroll
            for (int rr = 0; rr < 4; ++rr) {
                float v = acc[nt][rr] + bias;
                v = v > 0.f ? v : 0.f;
                sH[(wave * 16 + quad * 4 + rr) * LD64 + nt * 16 + l15] = (bf16)v;
            }
        }
        __syncthreads();

        f32x4 acc2[4];
        #pragma unroll
        for (int nt = 0; nt < 4; ++nt) acc2[nt] = (f32x4){0.f, 0.f, 0.f, 0.f};
        #pragma unroll
        for (int kt = 0; kt < 2; ++kt) {
            bf16x8 a = *(const bf16x8*)&sH[(wave * 16 + l15) * LD64 + kt * 32 + quad * 8];
            #pragma unroll
            for (int nt = 0; nt < 4; ++nt) {
                bf16x8 bfr = *(const bf16x8*)&sW2t[(nt * 16 + l15) * LD64 + kt * 32 + quad * 8];
                acc2[nt] = mfma16(a, bfr, acc2[nt]);
            }
        }
        #pragma unroll
        for (int nt = 0; nt < 4; ++nt) {
            float bias = sB2[nt * 16 + l15];
            #pragma unroll
            for (int rr = 0; rr < 4; ++rr) {
                int row = wave * 16 + quad * 4 + rr;
                int R = base + row;
                if (R < N)
                    out[(size_t)R * 64 + nt * 16 + l15] = acc2[nt][rr] + bias;
            }
        }
    }
}

// ===========================================================================
extern "C" void kernel_launch(void* const* d_in, const int* in_sizes, int n_in,
                              void* d_out, int out_size, void* d_ws, size_t ws_size,
                              hipStream_t stream) {
    const float* emb    = (const float*)d_in[0];
    const int*   rel1   = (const int*)d_in[1];
    const int*   rel2   = (const int*)d_in[2];
    const float* m1W1   = (const float*)d_in[3];
    const float* m1b1   = (const float*)d_in[4];
    const float* m1W2   = (const float*)d_in[5];
    const float* m1b2   = (const float*)d_in[6];
    const float* m2W1   = (const float*)d_in[7];
    const float* m2b1   = (const float*)d_in[8];
    const float* m2W2   = (const float*)d_in[9];
    const float* m2b2   = (const float*)d_in[10];
    const float* uW1    = (const float*)d_in[11];
    const float* ub1    = (const float*)d_in[12];
    const float* uW2    = (const float*)d_in[13];
    const float* ub2    = (const float*)d_in[14];

    const int N    = in_sizes[0] / 64;   // 100000
    const int M1   = in_sizes[1];        // 500000
    const int M2x2 = in_sizes[2];        // 2000000 (flat int count)

    // ---- workspace layout ----
    const int nch   = (N + 511) / 512;   // scan chunks over node bins
    const int nbins = nch * 512;         // padded bins
    char* wsb = (char*)d_ws;
    size_t off = 0;
    auto take = [&](size_t bytes) {
        size_t cur = off;
        off = (off + bytes + 255) & ~(size_t)255;
        return cur;
    };
    float*    agg  = (float*)   (wsb + take((size_t)N * 64 * sizeof(float)));
    unsigned* cnt1 = (unsigned*)(wsb + take((size_t)nbins * 4));
    unsigned* cnt2 = (unsigned*)(wsb + take((size_t)nbins * 4));
    unsigned* csum = (unsigned*)(wsb + take((size_t)(nch + 64) * 4));
    unsigned* s2id = (unsigned*)(wsb + take((size_t)M2x2 * 4));
    unsigned* s2pl = (unsigned*)(wsb + take((size_t)M2x2 * 4));

    if (off <= ws_size) {
        // ---- sorted-aggregation path ----
        // zero histogram bins (cnt1..cnt2 contiguous region incl. padding)
        hipMemsetAsync(cnt1, 0, (char*)csum - (char*)cnt1, stream);

        const int tot = M1 + M2x2;
        const int gh = ((tot + 255) / 256) < 2048 ? ((tot + 255) / 256) : 2048;
        hist_kernel<<<gh, 256, 0, stream>>>(rel1, rel2, cnt1, cnt2, M1, M2x2);

        scan_sums<<<nch, 256, 0, stream>>>(cnt2, csum);
        scan_chunkoff<<<1, 64, 0, stream>>>(csum, nch);
        scan_apply<<<nch, 256, 0, stream>>>(cnt2, csum);

        const int gp = ((M2x2 + 255) / 256) < 2048 ? ((M2x2 + 255) / 256) : 2048;
        place_kernel<<<gp, 256, 0, stream>>>(rel2, cnt2, s2id, s2pl, M2x2);

        // rel1 dense: writes every agg row (no memset of agg needed)
        const int t1 = (N + 63) / 64;
        rel1_dense_kernel<<<t1 < 2048 ? t1 : 2048, 256, 0, stream>>>(
            emb, cnt1, m1W1, m1b1, m1W2, m1b2, agg, N, t1);

        // rel2 aggregation over sorted stream
        const int t2 = (M2x2 + 63) / 64;
        rel2_agg_kernel<<<t2 < 2048 ? t2 : 2048, 256, 0, stream>>>(
            emb, rel2, s2id, s2pl, m2W1, m2b1, m2W2, m2b2, agg, M2x2, t2);

        const int tu = (N + 63) / 64;
        update_kernel<<<tu, 256, 0, stream>>>(emb, agg, uW1, ub1, uW2, ub2,
                                              (float*)d_out, N, tu);
    } else {
        // ---- fallback: Round-1 path (f16 agg + pk atomics) ----
        __half* aggh = (__half*)d_ws;
        hipMemsetAsync(aggh, 0, (size_t)N * 64 * sizeof(__half), stream);

        const int M2 = M2x2 / 2;
        const int t1 = (M1 + 63) / 64;
        rel1_fb_kernel<<<t1 < 1024 ? t1 : 1024, 256, 0, stream>>>(
            emb, rel1, m1W1, m1b1, m1W2, m1b2, aggh, M1, t1);
        const int t2 = (M2 + 63) / 64;
        rel2_fb_kernel<<<t2 < 2048 ? t2 : 2048, 256, 0, stream>>>(
            emb, rel2, m2W1, m2b1, m2W2, m2b2, aggh, M2, t2);
        const int tu = (N + 63) / 64;
        update_fb_kernel<<<tu, 256, 0, stream>>>(emb, aggh, uW1, ub1, uW2, ub2,
                                                 (float*)d_out, N, tu);
    }
}

// Round 4
// 670.641 us; speedup vs baseline: 1.1456x; 1.1456x over previous
//
#include <hip/hip_runtime.h>
#include <hip/hip_fp16.h>

typedef __bf16 bf16;
typedef bf16 bf16x8 __attribute__((ext_vector_type(8)));
typedef float f32x4 __attribute__((ext_vector_type(4)));

#define LD64  80   // padded LDS row stride (elems) for 64-wide tiles
#define LD128 144  // padded LDS row stride for 128-wide tiles

// Barrier that drains ONLY lgkmcnt (LDS visibility); does not drain vmcnt.
#define BAR_LGKM() asm volatile("s_waitcnt lgkmcnt(0)\n\ts_barrier" ::: "memory")

static __device__ __forceinline__ f32x4 mfma16(bf16x8 a, bf16x8 b, f32x4 c) {
    return __builtin_amdgcn_mfma_f32_16x16x32_bf16(a, b, c, 0, 0, 0);
}

static __device__ __forceinline__ bf16x8 cvt8(float4 a, float4 b) {
    bf16x8 v;
    v[0] = (bf16)a.x; v[1] = (bf16)a.y; v[2] = (bf16)a.z; v[3] = (bf16)a.w;
    v[4] = (bf16)b.x; v[5] = (bf16)b.y; v[6] = (bf16)b.z; v[7] = (bf16)b.w;
    return v;
}

// pack two f32 -> bf16x2 dword
static __device__ __forceinline__ uint32_t pack_bf16(float lo, float hi) {
    bf16 a = (bf16)lo, b = (bf16)hi;
    uint16_t ua = *(uint16_t*)&a, ub = *(uint16_t*)&b;
    return ((uint32_t)ub << 16) | (uint32_t)ua;
}

// --- helpers for the fallback (f16 agg) path ---
static __device__ __forceinline__ uint32_t pack_f16(float lo, float hi) {
    __half hl = __float2half_rn(lo), hh = __float2half_rn(hi);
    uint16_t a = *(uint16_t*)&hl, b = *(uint16_t*)&hh;
    return ((uint32_t)b << 16) | (uint32_t)a;
}
static __device__ __forceinline__ void atomic_pk_f16(__half* addr, uint32_t v) {
    asm volatile("global_atomic_pk_add_f16 %0, %1, off" :: "v"(addr), "v"(v) : "memory");
}
static __device__ __forceinline__ float h2f_lo(uint32_t u) {
    uint16_t s = (uint16_t)u; __half h = *(__half*)&s; return __half2float(h);
}
static __device__ __forceinline__ float h2f_hi(uint32_t u) {
    uint16_t s = (uint16_t)(u >> 16); __half h = *(__half*)&s; return __half2float(h);
}

// ===========================================================================
// Sort infrastructure: counting sort of rel2 (edge,slot) entries by dest node.
// Output: rowp[] CSR offsets + spl[] (flat rel2 index per sorted entry).
// ===========================================================================

__global__ __launch_bounds__(256) void hist_kernel(
    const int* __restrict__ r1, const int* __restrict__ r2,
    unsigned* __restrict__ cnt1, unsigned* __restrict__ cnt2, int M1, int M2x2)
{
    int i = blockIdx.x * 256 + threadIdx.x;
    const int T = gridDim.x * 256;
    const int tot = M1 + M2x2;
    for (; i < tot; i += T) {
        if (i < M1) atomicAdd(&cnt1[r1[i]], 1u);
        else        atomicAdd(&cnt2[r2[i - M1]], 1u);
    }
}

__global__ __launch_bounds__(256) void scan_sums(
    const unsigned* __restrict__ cnt, unsigned* __restrict__ csum)
{
    __shared__ unsigned s[256];
    const int b = blockIdx.x, t = threadIdx.x;
    s[t] = cnt[b * 512 + t] + cnt[b * 512 + 256 + t];
    __syncthreads();
    for (int d = 128; d > 0; d >>= 1) {
        if (t < d) s[t] += s[t + d];
        __syncthreads();
    }
    if (t == 0) csum[b] = s[0];
}

__global__ void scan_chunkoff(unsigned* __restrict__ csum, int nch) {
    if (blockIdx.x == 0 && threadIdx.x == 0) {
        unsigned run = 0;
        for (int j = 0; j < nch; ++j) { unsigned v = csum[j]; csum[j] = run; run += v; }
    }
}

// cnt2[i] <- global exclusive prefix (place cursor); rowp[i] <- preserved copy
__global__ __launch_bounds__(256) void scan_apply(
    unsigned* __restrict__ cnt, const unsigned* __restrict__ csum,
    unsigned* __restrict__ rowp)
{
    __shared__ unsigned s[2][512];
    const int b = blockIdx.x, t = threadIdx.x;
    const unsigned base = csum[b];
    s[0][t] = cnt[b * 512 + t];
    s[0][t + 256] = cnt[b * 512 + t + 256];
    __syncthreads();
    int src = 0;
    for (int d = 1; d < 512; d <<= 1) {
        int dst = src ^ 1;
        for (int i = t; i < 512; i += 256)
            s[dst][i] = s[src][i] + (i >= d ? s[src][i - d] : 0u);
        __syncthreads();
        src = dst;
    }
    for (int i = t; i < 512; i += 256) {
        unsigned excl = base + s[src][i] - cnt[b * 512 + i];
        cnt[b * 512 + i] = excl;
        rowp[b * 512 + i] = excl;
    }
}

// placement: spl[p] = flat index into r2 (edge*2+slot), sorted by dest node
__global__ __launch_bounds__(256) void place_kernel(
    const int* __restrict__ r2, unsigned* __restrict__ cur,
    unsigned* __restrict__ spl, int M2x2)
{
    int i = blockIdx.x * 256 + threadIdx.x;
    const int T = gridDim.x * 256;
    for (; i < M2x2; i += T) {
        int id = r2[i];
        unsigned p = atomicAdd(&cur[id], 1u);
        spl[p] = (unsigned)i;
    }
}

// ===========================================================================
// rel1 dense: agg[n] = cnt1[n] * (relu(emb[n]@W1+b1)@W2 + b2). No atomics.
// Writes EVERY agg row (replaces agg memset).
// ===========================================================================
__global__ __launch_bounds__(256) void rel1_dense_kernel(
    const float* __restrict__ emb, const unsigned* __restrict__ cnt,
    const float* __restrict__ W1, const float* __restrict__ b1,
    const float* __restrict__ W2, const float* __restrict__ b2,
    float* __restrict__ agg, int N, int numTiles)
{
    __shared__ bf16 sW1t[64 * LD64];
    __shared__ bf16 sW2t[64 * LD64];
    __shared__ bf16 sG[64 * LD64];
    __shared__ bf16 sH[64 * LD64];
    __shared__ float sB1[64], sB2[64];
    __shared__ float sCnt[64];

    const int t = threadIdx.x;
    const int wave = t >> 6, lane = t & 63;
    const int l15 = lane & 15, quad = lane >> 4;
    const int r = t >> 2, p = t & 3;

    for (int i = t; i < 64 * 64; i += 256) {
        int k = i >> 6, n = i & 63;
        sW1t[n * LD64 + k] = (bf16)W1[i];
        sW2t[n * LD64 + k] = (bf16)W2[i];
    }
    if (t < 64) { sB1[t] = b1[t]; sB2[t] = b2[t]; }

    for (int tile = blockIdx.x; tile < numTiles; tile += gridDim.x) {
        __syncthreads();
        const int base = tile * 64;
        const int R = base + r;
        if (R < N) {
            if (p == 0) sCnt[r] = (float)cnt[R];
            const float4* src = (const float4*)(emb + (size_t)R * 64 + p * 16);
            float4 v0 = src[0], v1 = src[1], v2 = src[2], v3 = src[3];
            *(bf16x8*)&sG[r * LD64 + p * 16 + 0] = cvt8(v0, v1);
            *(bf16x8*)&sG[r * LD64 + p * 16 + 8] = cvt8(v2, v3);
        } else if (p == 0) sCnt[r] = 0.f;
        __syncthreads();

        f32x4 acc[4];
        #pragma unroll
        for (int nt = 0; nt < 4; ++nt) acc[nt] = (f32x4){0.f, 0.f, 0.f, 0.f};
        #pragma unroll
        for (int kt = 0; kt < 2; ++kt) {
            bf16x8 a = *(const bf16x8*)&sG[(wave * 16 + l15) * LD64 + kt * 32 + quad * 8];
            #pragma unroll
            for (int nt = 0; nt < 4; ++nt) {
                bf16x8 bfr = *(const bf16x8*)&sW1t[(nt * 16 + l15) * LD64 + kt * 32 + quad * 8];
                acc[nt] = mfma16(a, bfr, acc[nt]);
            }
        }
        #pragma unroll
        for (int nt = 0; nt < 4; ++nt) {
            float bias = sB1[nt * 16 + l15];
            #pragma unroll
            for (int rr = 0; rr < 4; ++rr) {
                float v = acc[nt][rr] + bias;
                v = v > 0.f ? v : 0.f;
                sH[(wave * 16 + quad * 4 + rr) * LD64 + nt * 16 + l15] = (bf16)v;
            }
        }
        __syncthreads();

        f32x4 acc2[4];
        #pragma unroll
        for (int nt = 0; nt < 4; ++nt) acc2[nt] = (f32x4){0.f, 0.f, 0.f, 0.f};
        #pragma unroll
        for (int kt = 0; kt < 2; ++kt) {
            bf16x8 a = *(const bf16x8*)&sH[(wave * 16 + l15) * LD64 + kt * 32 + quad * 8];
            #pragma unroll
            for (int nt = 0; nt < 4; ++nt) {
                bf16x8 bfr = *(const bf16x8*)&sW2t[(nt * 16 + l15) * LD64 + kt * 32 + quad * 8];
                acc2[nt] = mfma16(a, bfr, acc2[nt]);
            }
        }
        #pragma unroll
        for (int nt = 0; nt < 4; ++nt) {
            float bias = sB2[nt * 16 + l15];
            #pragma unroll
            for (int rr = 0; rr < 4; ++rr) {
                int row = wave * 16 + quad * 4 + rr;
                int R2 = base + row;
                if (R2 < N)
                    agg[(size_t)R2 * 64 + nt * 16 + l15] = sCnt[row] * (acc2[nt][rr] + bias);
            }
        }
    }
}

// ===========================================================================
// PASS 1: rel2 message compute, each edge ONCE. msg[edge][128] bf16, linear
// paired stores, zero atomics.
// ===========================================================================
__global__ __launch_bounds__(256) void rel2_msg_kernel(
    const float* __restrict__ emb, const int* __restrict__ idx,  // [M][2]
    const float* __restrict__ W1, const float* __restrict__ b1,  // 128x128, 128
    const float* __restrict__ W2, const float* __restrict__ b2,
    bf16* __restrict__ msg, int M, int numTiles)
{
    __shared__ bf16 sG[64 * LD128];
    __shared__ bf16 sH[64 * LD128];

    const int t = threadIdx.x;
    const int wave = t >> 6, lane = t & 63;
    const int l15 = lane & 15, quad = lane >> 4;
    const int r = t >> 2, p = t & 3;

    // per-wave B fragments in registers: n-tiles {2*wave, 2*wave+1}
    bf16x8 w1f[2][4], w2f[2][4];
    float bias1[2], bias2[2];
    #pragma unroll
    for (int j = 0; j < 2; ++j) {
        const int n = (wave * 2 + j) * 16 + l15;
        bias1[j] = b1[n];
        bias2[j] = b2[n];
        #pragma unroll
        for (int kt = 0; kt < 4; ++kt) {
            bf16x8 f1, f2;
            #pragma unroll
            for (int e = 0; e < 8; ++e) {
                int k = kt * 32 + quad * 8 + e;
                f1[e] = (bf16)W1[k * 128 + n];
                f2[e] = (bf16)W2[k * 128 + n];
            }
            w1f[j][kt] = f1;
            w2f[j][kt] = f2;
        }
    }

    for (int tile = blockIdx.x; tile < numTiles; tile += gridDim.x) {
        BAR_LGKM();   // prev iter's GEMM2 sH reads + GEMM1 sG reads done
        const int base = tile * 64;
        const int R = base + r;
        if (R < M) {
            const int i0 = idx[R * 2], i1 = idx[R * 2 + 1];
            const int srcId = (p < 2) ? i0 : i1;
            const float4* src = (const float4*)(emb + (size_t)srcId * 64 + (p & 1) * 32);
            #pragma unroll
            for (int i = 0; i < 4; ++i)
                *(bf16x8*)&sG[r * LD128 + p * 32 + i * 8] = cvt8(src[2 * i], src[2 * i + 1]);
        }
        BAR_LGKM();

        // GEMM1 over all 4 m-tiles, this wave's 2 n-tiles
        f32x4 acc[4][2];
        #pragma unroll
        for (int mt = 0; mt < 4; ++mt)
            #pragma unroll
            for (int j = 0; j < 2; ++j) acc[mt][j] = (f32x4){0.f, 0.f, 0.f, 0.f};
        #pragma unroll
        for (int mt = 0; mt < 4; ++mt) {
            #pragma unroll
            for (int kt = 0; kt < 4; ++kt) {
                bf16x8 a = *(const bf16x8*)&sG[(mt * 16 + l15) * LD128 + kt * 32 + quad * 8];
                #pragma unroll
                for (int j = 0; j < 2; ++j) acc[mt][j] = mfma16(a, w1f[j][kt], acc[mt][j]);
            }
        }
        #pragma unroll
        for (int mt = 0; mt < 4; ++mt)
            #pragma unroll
            for (int j = 0; j < 2; ++j) {
                #pragma unroll
                for (int rr = 0; rr < 4; ++rr) {
                    float v = acc[mt][j][rr] + bias1[j];
                    v = v > 0.f ? v : 0.f;
                    sH[(mt * 16 + quad * 4 + rr) * LD128 + (wave * 2 + j) * 16 + l15] = (bf16)v;
                }
            }
        BAR_LGKM();

        // GEMM2 -> linear paired stores to msg[edge][128]
        f32x4 acc2[4][2];
        #pragma unroll
        for (int mt = 0; mt < 4; ++mt)
            #pragma unroll
            for (int j = 0; j < 2; ++j) acc2[mt][j] = (f32x4){0.f, 0.f, 0.f, 0.f};
        #pragma unroll
        for (int mt = 0; mt < 4; ++mt) {
            #pragma unroll
            for (int kt = 0; kt < 4; ++kt) {
                bf16x8 a = *(const bf16x8*)&sH[(mt * 16 + l15) * LD128 + kt * 32 + quad * 8];
                #pragma unroll
                for (int j = 0; j < 2; ++j) acc2[mt][j] = mfma16(a, w2f[j][kt], acc2[mt][j]);
            }
        }
        #pragma unroll
        for (int mt = 0; mt < 4; ++mt) {
            #pragma unroll
            for (int j = 0; j < 2; ++j) {
                const int colb = (wave * 2 + j) * 16 + (l15 & ~1);  // even col of pair
                const int odd = l15 & 1;
                #pragma unroll
                for (int rr = 0; rr < 4; ++rr) {
                    float v = acc2[mt][j][rr] + bias2[j];
                    float o = __shfl_xor(v, 1);
                    if ((rr >> 1) == odd) {
                        int row = mt * 16 + quad * 4 + rr;
                        int E = base + row;
                        if (E < M)
                            *(uint32_t*)&msg[(size_t)E * 128 + colb] =
                                odd ? pack_bf16(o, v) : pack_bf16(v, o);
                    }
                }
            }
        }
    }
}

// ===========================================================================
// PASS 2: node-owned aggregation over the dest-sorted entry list. Wave owns
// 16 nodes; per node, sum msg[spl[e]][lane] over its CSR range and do ONE
// non-atomic read-modify-write of agg row (rel1 term already there).
// ===========================================================================
__global__ __launch_bounds__(256) void rel2_agg2_kernel(
    const bf16* __restrict__ msg, const unsigned* __restrict__ spl,
    const unsigned* __restrict__ rowp, float* __restrict__ agg,
    int N, int numTiles)
{
    const int lane = threadIdx.x & 63;
    const int w = threadIdx.x >> 6;

    for (int tile = blockIdx.x; tile < numTiles; tile += gridDim.x) {
        const int n0 = tile * 64 + w * 16;
        #pragma unroll 1
        for (int k = 0; k < 16; ++k) {
            const int n = n0 + k;
            if (n >= N) break;
            unsigned e = rowp[n];
            const unsigned end = rowp[n + 1];
            float run = 0.f;
            // 4-deep unrolled: 4 independent random 128B wave-loads in flight
            for (; e + 4 <= end; e += 4) {
                unsigned p0 = spl[e], p1 = spl[e + 1], p2 = spl[e + 2], p3 = spl[e + 3];
                float v0 = (float)msg[(size_t)p0 * 64 + lane];
                float v1 = (float)msg[(size_t)p1 * 64 + lane];
                float v2 = (float)msg[(size_t)p2 * 64 + lane];
                float v3 = (float)msg[(size_t)p3 * 64 + lane];
                run += (v0 + v1) + (v2 + v3);
            }
            for (; e < end; ++e)
                run += (float)msg[(size_t)spl[e] * 64 + lane];
            agg[(size_t)n * 64 + lane] += run;
        }
    }
}

// ===========================================================================
// update: out = relu([emb||agg] @ W1 + b1) @ W2 + b2   (agg f32)
// ===========================================================================
__global__ __launch_bounds__(256) void update_kernel(
    const float* __restrict__ emb, const float* __restrict__ agg,
    const float* __restrict__ W1, const float* __restrict__ b1,  // 128x64, 64
    const float* __restrict__ W2, const float* __restrict__ b2,  // 64x64, 64
    float* __restrict__ out, int N, int numTiles)
{
    __shared__ bf16 sW1t[64 * LD128];
    __shared__ bf16 sW2t[64 * LD64];
    __shared__ bf16 sU[64 * LD128];
    __shared__ bf16 sH[64 * LD64];
    __shared__ float sB1[64], sB2[64];

    const int t = threadIdx.x;
    const int wave = t >> 6, lane = t & 63;
    const int l15 = lane & 15, quad = lane >> 4;
    const int r = t >> 2, p = t & 3;

    for (int i = t; i < 128 * 64; i += 256) {
        int k = i >> 6, n = i & 63;
        sW1t[n * LD128 + k] = (bf16)W1[i];
    }
    for (int i = t; i < 64 * 64; i += 256) {
        int k = i >> 6, n = i & 63;
        sW2t[n * LD64 + k] = (bf16)W2[i];
    }
    if (t < 64) { sB1[t] = b1[t]; sB2[t] = b2[t]; }

    for (int tile = blockIdx.x; tile < numTiles; tile += gridDim.x) {
        __syncthreads();
        const int base = tile * 64;
        {
            const int R = base + r;
            if (R < N) {
                const float* srcp = (p < 2) ? (emb + (size_t)R * 64 + p * 32)
                                            : (agg + (size_t)R * 64 + (p - 2) * 32);
                const float4* src = (const float4*)srcp;
                #pragma unroll
                for (int i = 0; i < 4; ++i)
                    *(bf16x8*)&sU[r * LD128 + p * 32 + i * 8] = cvt8(src[2 * i], src[2 * i + 1]);
            }
        }
        __syncthreads();

        f32x4 acc[4];
        #pragma unroll
        for (int nt = 0; nt < 4; ++nt) acc[nt] = (f32x4){0.f, 0.f, 0.f, 0.f};
        #pragma unroll
        for (int kt = 0; kt < 4; ++kt) {
            bf16x8 a = *(const bf16x8*)&sU[(wave * 16 + l15) * LD128 + kt * 32 + quad * 8];
            #pragma unroll
            for (int nt = 0; nt < 4; ++nt) {
                bf16x8 bfr = *(const bf16x8*)&sW1t[(nt * 16 + l15) * LD128 + kt * 32 + quad * 8];
                acc[nt] = mfma16(a, bfr, acc[nt]);
            }
        }
        #pragma unroll
        for (int nt = 0; nt < 4; ++nt) {
            float bias = sB1[nt * 16 + l15];
            #pragma unroll
            for (int rr = 0; rr < 4; ++rr) {
                float v = acc[nt][rr] + bias;
                v = v > 0.f ? v : 0.f;
                sH[(wave * 16 + quad * 4 + rr) * LD64 + nt * 16 + l15] = (bf16)v;
            }
        }
        __syncthreads();

        f32x4 acc2[4];
        #pragma unroll
        for (int nt = 0; nt < 4; ++nt) acc2[nt] = (f32x4){0.f, 0.f, 0.f, 0.f};
        #pragma unroll
        for (int kt = 0; kt < 2; ++kt) {
            bf16x8 a = *(const bf16x8*)&sH[(wave * 16 + l15) * LD64 + kt * 32 + quad * 8];
            #pragma unroll
            for (int nt = 0; nt < 4; ++nt) {
                bf16x8 bfr = *(const bf16x8*)&sW2t[(nt * 16 + l15) * LD64 + kt * 32 + quad * 8];
                acc2[nt] = mfma16(a, bfr, acc2[nt]);
            }
        }
        #pragma unroll
        for (int nt = 0; nt < 4; ++nt) {
            float bias = sB2[nt * 16 + l15];
            #pragma unroll
            for (int rr = 0; rr < 4; ++rr) {
                int row = wave * 16 + quad * 4 + rr;
                int R = base + row;
                if (R < N)
                    out[(size_t)R * 64 + nt * 16 + l15] = acc2[nt][rr] + bias;
            }
        }
    }
}

// ===========================================================================
// Fallback path (workspace too small): Round-1 kernels (f16 agg, pk atomics).
// ===========================================================================
__global__ __launch_bounds__(256) void rel1_fb_kernel(
    const float* __restrict__ emb, const int* __restrict__ idx,
    const float* __restrict__ W1, const float* __restrict__ b1,
    const float* __restrict__ W2, const float* __restrict__ b2,
    __half* __restrict__ agg, int M, int numTiles)
{
    __shared__ bf16 sW1t[64 * LD64];
    __shared__ bf16 sW2t[64 * LD64];
    __shared__ bf16 sG[64 * LD64];
    __shared__ bf16 sH[64 * LD64];
    __shared__ float sB1[64], sB2[64];
    __shared__ int sIdx[64];

    const int t = threadIdx.x;
    const int wave = t >> 6, lane = t & 63;
    const int l15 = lane & 15, quad = lane >> 4;
    const int r = t >> 2, p = t & 3;

    for (int i = t; i < 64 * 64; i += 256) {
        int k = i >> 6, n = i & 63;
        sW1t[n * LD64 + k] = (bf16)W1[i];
        sW2t[n * LD64 + k] = (bf16)W2[i];
    }
    if (t < 64) { sB1[t] = b1[t]; sB2[t] = b2[t]; }

    for (int tile = blockIdx.x; tile < numTiles; tile += gridDim.x) {
        __syncthreads();
        const int base = tile * 64;
        int id = -1;
        { int R = base + r; if (R < M) id = idx[R]; }
        if (p == 0) sIdx[r] = id;
        if (id >= 0) {
            const float4* src = (const float4*)(emb + (size_t)id * 64 + p * 16);
            float4 v0 = src[0], v1 = src[1], v2 = src[2], v3 = src[3];
            *(bf16x8*)&sG[r * LD64 + p * 16 + 0] = cvt8(v0, v1);
            *(bf16x8*)&sG[r * LD64 + p * 16 + 8] = cvt8(v2, v3);
        }
        __syncthreads();

        f32x4 acc[4];
        #pragma unroll
        for (int nt = 0; nt < 4; ++nt) acc[nt] = (f32x4){0.f, 0.f, 0.f, 0.f};
        #pragma unroll
        for (int kt = 0; kt < 2; ++kt) {
            bf16x8 a = *(const bf16x8*)&sG[(wave * 16 + l15) * LD64 + kt * 32 + quad * 8];
            #pragma unroll
            for (int nt = 0; nt < 4; ++nt) {
                bf16x8 bfr = *(const bf16x8*)&sW1t[(nt * 16 + l15) * LD64 + kt * 32 + quad * 8];
                acc[nt] = mfma16(a, bfr, acc[nt]);
            }
        }
        #pragma unroll
        for (int nt = 0; nt < 4; ++nt) {
            float bias = sB1[nt * 16 + l15];
            #pragma unroll
            for (int rr = 0; rr < 4; ++rr) {
                float v = acc[nt][rr] + bias;
                v = v > 0.f ? v : 0.f;
                sH[(wave * 16 + quad * 4 + rr) * LD64 + nt * 16 + l15] = (bf16)v;
            }
        }
        __syncthreads();

        f32x4 acc2[4];
        #pragma unroll
        for (int nt = 0; nt < 4; ++nt) acc2[nt] = (f32x4){0.f, 0.f, 0.f, 0.f};
        #pragma unroll
        for (int kt = 0; kt < 2; ++kt) {
            bf16x8 a = *(const bf16x8*)&sH[(wave * 16 + l15) * LD64 + kt * 32 + quad * 8];
            #pragma unroll
            for (int nt = 0; nt < 4; ++nt) {
                bf16x8 bfr = *(const bf16x8*)&sW2t[(nt * 16 + l15) * LD64 + kt * 32 + quad * 8];
                acc2[nt] = mfma16(a, bfr, acc2[nt]);
            }
        }
        #pragma unroll
        for (int nt = 0; nt < 4; ++nt) {
            float bias = sB2[nt * 16 + l15];
            const int colb = nt * 16 + (l15 & ~1);
            const int odd = l15 & 1;
            #pragma unroll
            for (int rr = 0; rr < 4; ++rr) {
                float v = acc2[nt][rr] + bias;
                float o = __shfl_xor(v, 1);
                if ((rr >> 1) == odd) {
                    int row = wave * 16 + quad * 4 + rr;
                    int id2 = sIdx[row];
                    if (id2 >= 0)
                        atomic_pk_f16(agg + (size_t)id2 * 64 + colb,
                                      odd ? pack_f16(o, v) : pack_f16(v, o));
                }
            }
        }
    }
}

__global__ __launch_bounds__(256) void rel2_fb_kernel(
    const float* __restrict__ emb, const int* __restrict__ idx,
    const float* __restrict__ W1, const float* __restrict__ b1,
    const float* __restrict__ W2, const float* __restrict__ b2,
    __half* __restrict__ agg, int M, int numTiles)
{
    __shared__ bf16 sG[64 * LD128];
    __shared__ bf16 sH[64 * LD128];
    __shared__ int sIdx[128];

    const int t = threadIdx.x;
    const int wave = t >> 6, lane = t & 63;
    const int l15 = lane & 15, quad = lane >> 4;
    const int r = t >> 2, p = t & 3;

    bf16x8 w1f[2][4], w2f[2][4];
    float bias1[2], bias2[2];
    #pragma unroll
    for (int j = 0; j < 2; ++j) {
        const int n = (wave * 2 + j) * 16 + l15;
        bias1[j] = b1[n];
        bias2[j] = b2[n];
        #pragma unroll
        for (int kt = 0; kt < 4; ++kt) {
            bf16x8 f1, f2;
            #pragma unroll
            for (int e = 0; e < 8; ++e) {
                int k = kt * 32 + quad * 8 + e;
                f1[e] = (bf16)W1[k * 128 + n];
                f2[e] = (bf16)W2[k * 128 + n];
            }
            w1f[j][kt] = f1;
            w2f[j][kt] = f2;
        }
    }

    for (int tile = blockIdx.x; tile < numTiles; tile += gridDim.x) {
        __syncthreads();
        const int base = tile * 64;
        int i0 = -1, i1 = -1;
        { int R = base + r; if (R < M) { i0 = idx[R * 2]; i1 = idx[R * 2 + 1]; } }
        if (p == 0) { sIdx[r * 2] = i0; sIdx[r * 2 + 1] = i1; }
        {
            int myid = (p < 2) ? i0 : i1;
            if (myid >= 0) {
                const float4* src = (const float4*)(emb + (size_t)myid * 64 + (p & 1) * 32);
                #pragma unroll
                for (int i = 0; i < 4; ++i)
                    *(bf16x8*)&sG[r * LD128 + p * 32 + i * 8] = cvt8(src[2 * i], src[2 * i + 1]);
            }
        }
        __syncthreads();

        f32x4 acc[4][2];
        #pragma unroll
        for (int mt = 0; mt < 4; ++mt)
            #pragma unroll
            for (int j = 0; j < 2; ++j) acc[mt][j] = (f32x4){0.f, 0.f, 0.f, 0.f};
        #pragma unroll
        for (int mt = 0; mt < 4; ++mt) {
            #pragma unroll
            for (int kt = 0; kt < 4; ++kt) {
                bf16x8 a = *(const bf16x8*)&sG[(mt * 16 + l15) * LD128 + kt * 32 + quad * 8];
                #pragma unroll
                for (int j = 0; j < 2; ++j) acc[mt][j] = mfma16(a, w1f[j][kt], acc[mt][j]);
            }
        }
        #pragma unroll
        for (int mt = 0; mt < 4; ++mt)
            #pragma unroll
            for (int j = 0; j < 2; ++j) {
                #pragma unroll
                for (int rr = 0; rr < 4; ++rr) {
                    float v = acc[mt][j][rr] + bias1[j];
                    v = v > 0.f ? v : 0.f;
                    sH[(mt * 16 + quad * 4 + rr) * LD128 + (wave * 2 + j) * 16 + l15] = (bf16)v;
                }
            }
        __syncthreads();

        f32x4 acc2[4][2];
        #pragma unroll
        for (int mt = 0; mt < 4; ++mt)
            #pragma unroll
            for (int j = 0; j < 2; ++j) acc2[mt][j] = (f32x4){0.f, 0.f, 0.f, 0.f};
        #pragma unroll
        for (int mt = 0; mt < 4; ++mt) {
            #pragma unroll
            for (int kt = 0; kt < 4; ++kt) {
                bf16x8 a = *(const bf16x8*)&sH[(mt * 16 + l15) * LD128 + kt * 32 + quad * 8];
                #pragma unroll
                for (int j = 0; j < 2; ++j) acc2[mt][j] = mfma16(a, w2f[j][kt], acc2[mt][j]);
            }
        }
        #pragma unroll
        for (int mt = 0; mt < 4; ++mt) {
            #pragma unroll
            for (int j = 0; j < 2; ++j) {
                const int colb = (wave * 2 + j) * 16 + (l15 & ~1);
                const int sel = colb >> 6;
                const int c = colb & 63;
                const int odd = l15 & 1;
                #pragma unroll
                for (int rr = 0; rr < 4; ++rr) {
                    float v = acc2[mt][j][rr] + bias2[j];
                    float o = __shfl_xor(v, 1);
                    if ((rr >> 1) == odd) {
                        int row = mt * 16 + quad * 4 + rr;
                        int id2 = sIdx[row * 2 + sel];
                        if (id2 >= 0)
                            atomic_pk_f16(agg + (size_t)id2 * 64 + c,
                                          odd ? pack_f16(o, v) : pack_f16(v, o));
                    }
                }
            }
        }
    }
}

__global__ __launch_bounds__(256) void update_fb_kernel(
    const float* __restrict__ emb, const __half* __restrict__ agg,
    const float* __restrict__ W1, const float* __restrict__ b1,
    const float* __restrict__ W2, const float* __restrict__ b2,
    float* __restrict__ out, int N, int numTiles)
{
    __shared__ bf16 sW1t[64 * LD128];
    __shared__ bf16 sW2t[64 * LD64];
    __shared__ bf16 sU[64 * LD128];
    __shared__ bf16 sH[64 * LD64];
    __shared__ float sB1[64], sB2[64];

    const int t = threadIdx.x;
    const int wave = t >> 6, lane = t & 63;
    const int l15 = lane & 15, quad = lane >> 4;
    const int r = t >> 2, p = t & 3;

    for (int i = t; i < 128 * 64; i += 256) {
        int k = i >> 6, n = i & 63;
        sW1t[n * LD128 + k] = (bf16)W1[i];
    }
    for (int i = t; i < 64 * 64; i += 256) {
        int k = i >> 6, n = i & 63;
        sW2t[n * LD64 + k] = (bf16)W2[i];
    }
    if (t < 64) { sB1[t] = b1[t]; sB2[t] = b2[t]; }

    for (int tile = blockIdx.x; tile < numTiles; tile += gridDim.x) {
        __syncthreads();
        const int base = tile * 64;
        {
            const int R = base + r;
            if (R < N) {
                if (p < 2) {
                    const float4* src = (const float4*)(emb + (size_t)R * 64 + p * 32);
                    #pragma unroll
                    for (int i = 0; i < 4; ++i)
                        *(bf16x8*)&sU[r * LD128 + p * 32 + i * 8] = cvt8(src[2 * i], src[2 * i + 1]);
                } else {
                    const uint4* src = (const uint4*)(agg + (size_t)R * 64 + (p - 2) * 32);
                    #pragma unroll
                    for (int i = 0; i < 4; ++i) {
                        uint4 u = src[i];
                        bf16x8 o;
                        o[0] = (bf16)h2f_lo(u.x); o[1] = (bf16)h2f_hi(u.x);
                        o[2] = (bf16)h2f_lo(u.y); o[3] = (bf16)h2f_hi(u.y);
                        o[4] = (bf16)h2f_lo(u.z); o[5] = (bf16)h2f_hi(u.z);
                        o[6] = (bf16)h2f_lo(u.w); o[7] = (bf16)h2f_hi(u.w);
                        *(bf16x8*)&sU[r * LD128 + p * 32 + i * 8] = o;
                    }
                }
            }
        }
        __syncthreads();

        f32x4 acc[4];
        #pragma unroll
        for (int nt = 0; nt < 4; ++nt) acc[nt] = (f32x4){0.f, 0.f, 0.f, 0.f};
        #pragma unroll
        for (int kt = 0; kt < 4; ++kt) {
            bf16x8 a = *(const bf16x8*)&sU[(wave * 16 + l15) * LD128 + kt * 32 + quad * 8];
            #pragma unroll
            for (int nt = 0; nt < 4; ++nt) {
                bf16x8 bfr = *(const bf16x8*)&sW1t[(nt * 16 + l15) * LD128 + kt * 32 + quad * 8];
                acc[nt] = mfma16(a, bfr, acc[nt]);
            }
        }
        #pragma unroll
        for (int nt = 0; nt < 4; ++nt) {
            float bias = sB1[nt * 16 + l15];
            #pragma unroll
            for (int rr = 0; rr < 4; ++rr) {
                float v = acc[nt][rr] + bias;
                v = v > 0.f ? v : 0.f;
                sH[(wave * 16 + quad * 4 + rr) * LD64 + nt * 16 + l15] = (bf16)v;
            }
        }
        __syncthreads();

        f32x4 acc2[4];
        #pragma unroll
        for (int nt = 0; nt < 4; ++nt) acc2[nt] = (f32x4){0.f, 0.f, 0.f, 0.f};
        #pragma unroll
        for (int kt = 0; kt < 2; ++kt) {
            bf16x8 a = *(const bf16x8*)&sH[(wave * 16 + l15) * LD64 + kt * 32 + quad * 8];
            #pragma unroll
            for (int nt = 0; nt < 4; ++nt) {
                bf16x8 bfr = *(const bf16x8*)&sW2t[(nt * 16 + l15) * LD64 + kt * 32 + quad * 8];
                acc2[nt] = mfma16(a, bfr, acc2[nt]);
            }
        }
        #pragma unroll
        for (int nt = 0; nt < 4; ++nt) {
            float bias = sB2[nt * 16 + l15];
            #pragma unroll
            for (int rr = 0; rr < 4; ++rr) {
                int row = wave * 16 + quad * 4 + rr;
                int R = base + row;
                if (R < N)
                    out[(size_t)R * 64 + nt * 16 + l15] = acc2[nt][rr] + bias;
            }
        }
    }
}

// ===========================================================================
extern "C" void kernel_launch(void* const* d_in, const int* in_sizes, int n_in,
                              void* d_out, int out_size, void* d_ws, size_t ws_size,
                              hipStream_t stream) {
    const float* emb    = (const float*)d_in[0];
    const int*   rel1   = (const int*)d_in[1];
    const int*   rel2   = (const int*)d_in[2];
    const float* m1W1   = (const float*)d_in[3];
    const float* m1b1   = (const float*)d_in[4];
    const float* m1W2   = (const float*)d_in[5];
    const float* m1b2   = (const float*)d_in[6];
    const float* m2W1   = (const float*)d_in[7];
    const float* m2b1   = (const float*)d_in[8];
    const float* m2W2   = (const float*)d_in[9];
    const float* m2b2   = (const float*)d_in[10];
    const float* uW1    = (const float*)d_in[11];
    const float* ub1    = (const float*)d_in[12];
    const float* uW2    = (const float*)d_in[13];
    const float* ub2    = (const float*)d_in[14];

    const int N    = in_sizes[0] / 64;   // 100000
    const int M1   = in_sizes[1];        // 500000
    const int M2x2 = in_sizes[2];        // 2000000 (flat int count)
    const int M2   = M2x2 / 2;

    // ---- workspace layout ----
    const int nch   = (N + 511) / 512;
    const int nbins = nch * 512;         // > N, so rowp[N] is valid
    char* wsb = (char*)d_ws;
    size_t off = 0;
    auto take = [&](size_t bytes) {
        size_t cur = off;
        off = (off + bytes + 255) & ~(size_t)255;
        return cur;
    };
    float*    agg  = (float*)   (wsb + take((size_t)N * 64 * sizeof(float)));
    unsigned* cnt1 = (unsigned*)(wsb + take((size_t)nbins * 4));
    unsigned* cnt2 = (unsigned*)(wsb + take((size_t)nbins * 4));
    unsigned* rowp = (unsigned*)(wsb + take((size_t)nbins * 4));
    unsigned* csum = (unsigned*)(wsb + take((size_t)(nch + 64) * 4));
    unsigned* spl  = (unsigned*)(wsb + take((size_t)M2x2 * 4));
    bf16*     msg  = (bf16*)    (wsb + take((size_t)M2 * 128 * sizeof(bf16)));

    if (off <= ws_size) {
        // ---- sorted two-pass path ----
        hipMemsetAsync(cnt1, 0, (size_t)nbins * 2 * 4, stream);  // cnt1 + cnt2

        const int tot = M1 + M2x2;
        const int gh = ((tot + 255) / 256) < 2048 ? ((tot + 255) / 256) : 2048;
        hist_kernel<<<gh, 256, 0, stream>>>(rel1, rel2, cnt1, cnt2, M1, M2x2);

        scan_sums<<<nch, 256, 0, stream>>>(cnt2, csum);
        scan_chunkoff<<<1, 64, 0, stream>>>(csum, nch);
        scan_apply<<<nch, 256, 0, stream>>>(cnt2, csum, rowp);

        const int gp = ((M2x2 + 255) / 256) < 2048 ? ((M2x2 + 255) / 256) : 2048;
        place_kernel<<<gp, 256, 0, stream>>>(rel2, cnt2, spl, M2x2);

        // pass 1: edge messages, each edge once, linear bf16 stores
        const int tm = (M2 + 63) / 64;
        rel2_msg_kernel<<<tm < 2048 ? tm : 2048, 256, 0, stream>>>(
            emb, rel2, m2W1, m2b1, m2W2, m2b2, msg, M2, tm);

        // rel1 dense (writes every agg row)
        const int t1 = (N + 63) / 64;
        rel1_dense_kernel<<<t1 < 2048 ? t1 : 2048, 256, 0, stream>>>(
            emb, cnt1, m1W1, m1b1, m1W2, m1b2, agg, N, t1);

        // pass 2: node-owned CSR aggregation, no atomics
        rel2_agg2_kernel<<<t1 < 2048 ? t1 : 2048, 256, 0, stream>>>(
            msg, spl, rowp, agg, N, t1);

        update_kernel<<<t1, 256, 0, stream>>>(emb, agg, uW1, ub1, uW2, ub2,
                                              (float*)d_out, N, t1);
    } else {
        // ---- fallback: Round-1 path (f16 agg + pk atomics) ----
        __half* aggh = (__half*)d_ws;
        hipMemsetAsync(aggh, 0, (size_t)N * 64 * sizeof(__half), stream);

        const int t1 = (M1 + 63) / 64;
        rel1_fb_kernel<<<t1 < 1024 ? t1 : 1024, 256, 0, stream>>>(
            emb, rel1, m1W1, m1b1, m1W2, m1b2, aggh, M1, t1);
        const int t2 = (M2 + 63) / 64;
        rel2_fb_kernel<<<t2 < 2048 ? t2 : 2048, 256, 0, stream>>>(
            emb, rel2, m2W1, m2b1, m2W2, m2b2, aggh, M2, t2);
        const int tu = (N + 63) / 64;
        update_fb_kernel<<<tu, 256, 0, stream>>>(emb, aggh, uW1, ub1, uW2, ub2,
                                                 (float*)d_out, N, tu);
    }
}